// Round 1
// baseline (1452.899 us; speedup 1.0000x reference)
//
#include <hip/hip_runtime.h>
#include <hip/hip_bf16.h>
#include <math.h>

typedef __attribute__((ext_vector_type(8))) short short8;
typedef __attribute__((ext_vector_type(4))) float f32x4;
typedef unsigned short u16;
typedef unsigned int u32;

__device__ __forceinline__ u16 f2bf(float f) {
  union { float f; u32 u; } x; x.f = f;
  return (u16)((x.u + 0x7fffu + ((x.u >> 16) & 1u)) >> 16);
}
__device__ __forceinline__ float sigm(float v) { return 1.0f / (1.0f + __expf(-v)); }

#define MFMA __builtin_amdgcn_mfma_f32_16x16x32_bf16

// Persistent fused 2-layer GRU.
// Grid: 256 WGs = 4 row-blocks (128 rows) x 2 layers x 32 col-blocks (16 hidden cols).
// Phase p: layer-0 WGs compute h1(p) [p in 0..63]; layer-1 WGs compute h2(p-1) [p in 1..64].
// Per-row-block barrier (64 WGs) between phases; weights live in LDS in MFMA-fragment order.
__global__ __launch_bounds__(256, 1) void gru_fused(
    const float* __restrict__ xin, const float* __restrict__ h1in, const float* __restrict__ h2in,
    const float* __restrict__ Wih1, const float* __restrict__ Whh1,
    const float* __restrict__ bih1, const float* __restrict__ bhh1,
    const float* __restrict__ Wih2, const float* __restrict__ Whh2,
    const float* __restrict__ bih2, const float* __restrict__ bhh2,
    const float* __restrict__ Wfc, const float* __restrict__ bfc,
    float* __restrict__ out, u16* __restrict__ wsb, unsigned* __restrict__ barc)
{
  const int bid   = blockIdx.x;
  const int rb    = bid & 3;          // row-block 0..3 (128 rows each)
  const int layer = (bid >> 2) & 1;   // 0: GRU1, 1: GRU2
  const int cbl   = bid >> 3;         // col-block 0..31 (16 hidden cols)
  const int n0    = cbl * 16;
  const int wid   = bid >> 2;         // 0..63 unique within row-block
  const int tid   = threadIdx.x;
  const int w     = tid >> 6;         // wave 0..3
  const int lane  = tid & 63;
  const int quad  = lane >> 4;
  const int m16   = lane & 15;

  // workspace layout (u16 elements)
  u16* x0 = wsb;                      // x bf16, pitch 576
  u16* x1 = x0 + 512 * 576;           // x shifted by 1 (for odd t alignment)
  u16* h1b[2]; u16* h2b[2];
  h1b[0] = x1 + 512 * 576;
  h1b[1] = h1b[0] + 512 * 512;
  h2b[0] = h1b[1] + 512 * 512;
  h2b[1] = h2b[0] + 512 * 512;

  // 96 blocks of 1KB: [0,32)=r, [32,64)=z, [64,80)=i_n (K-steps 0..15), [80,96)=h_n (K-steps 16..31)
  __shared__ short8 wlds[96 * 64];    // 98304 B

  unsigned* ctr = barc + rb * 16;

  const float* Wih = layer ? Wih2 : Wih1;
  const float* Whh = layer ? Whh2 : Whh1;
  const float* bih = layer ? bih2 : bih1;
  const float* bhh = layer ? bhh2 : bhh1;

  // ---------------- one-time init ----------------
  // x -> bf16, two shifted copies (row-block local)
  for (int i = wid * 256 + tid; i < 128 * 575; i += 64 * 256) {
    int r = i / 575, c = i - r * 575;
    int row = rb * 128 + r;
    u16 bv = f2bf(xin[row * 575 + c]);
    x0[row * 576 + c] = bv;
    if (c >= 1) x1[row * 576 + (c - 1)] = bv;
  }
  // h states read at phase 0 (h1b[0]) and phase 1 (h2b[1])
  for (int i = wid * 256 + tid; i < 128 * 512; i += 64 * 256) {
    int r = i >> 9, c = i & 511;
    int row = rb * 128 + r;
    h1b[0][row * 512 + c] = f2bf(h1in[row * 512 + c]);
    h2b[1][row * 512 + c] = f2bf(h2in[row * 512 + c]);
  }
  // weights -> LDS in B-fragment order: lane holds B[k = s*32 + (lane>>4)*8 + j][n = n0 + (lane&15)]
  for (int i = tid; i < 96 * 64; i += 256) {
    int blk = i >> 6, l = i & 63;
    int s, gr;
    if (blk < 64) { s = blk & 31; gr = (blk >> 5) * 512; }   // r (gr=0) / z (gr=512)
    else          { s = blk - 64; gr = 1024; }               // i_n (s<16) / h_n (s>=16)
    int n  = n0 + (l & 15);
    int k0 = s * 32 + (l >> 4) * 8;
    short8 pk;
    #pragma unroll
    for (int j = 0; j < 8; ++j) {
      int k = k0 + j;
      float v = (k < 512) ? Wih[(gr + n) * 512 + k] : Whh[(gr + n) * 512 + (k - 512)];
      pk[j] = (short)f2bf(v);
    }
    wlds[blk * 64 + l] = pk;
  }

  // own h-state tile in fp32 registers (C-layout: row = quad*4+q, col = m16)
  float hreg[2][4];
  const float* hin = layer ? h2in : h1in;
  #pragma unroll
  for (int rf = 0; rf < 2; ++rf)
    #pragma unroll
    for (int q = 0; q < 4; ++q)
      hreg[rf][q] = hin[(rb * 128 + (2 * w + rf) * 16 + quad * 4 + q) * 512 + n0 + m16];

  const int nn = n0 + m16;
  const float bias_r  = bih[nn] + bhh[nn];
  const float bias_z  = bih[512 + nn] + bhh[512 + nn];
  const float bias_in = bih[1024 + nn];
  const float bias_hn = bhh[1024 + nn];
  const float wfc  = Wfc[nn];
  const float bfcv = bfc[0];

  unsigned epoch = 0;
  #define RB_BARRIER()                                                                   \
    do {                                                                                 \
      __syncthreads();                                                                   \
      ++epoch;                                                                           \
      if (tid == 0) {                                                                    \
        __threadfence();                                                                 \
        __hip_atomic_fetch_add(ctr, 1u, __ATOMIC_RELAXED, __HIP_MEMORY_SCOPE_AGENT);     \
        while (__hip_atomic_load(ctr, __ATOMIC_RELAXED, __HIP_MEMORY_SCOPE_AGENT) <      \
               epoch * 64u)                                                              \
          __builtin_amdgcn_s_sleep(2);                                                   \
        __threadfence();                                                                 \
      }                                                                                  \
      __syncthreads();                                                                   \
    } while (0)

  RB_BARRIER();

  const int arow0 = rb * 128 + (2 * w) * 16 + m16;  // A-frag row (A-layout: m = lane&15)
  const int arow1 = arow0 + 16;

  for (int p = 0; p <= 64; ++p) {
    const bool active = layer ? (p >= 1) : (p < 64);
    if (active) {
      const int t   = layer ? (p - 1) : p;
      const int cur = p & 1;
      f32x4 acc[2][4] = {};   // [row-frag][gate r,z,in,hn]

      // ---- K first half (input operand): gates r, z, i_n ----
      if (layer == 0) {
        const int c = t & 1;                 // pick shifted copy so element offset is even
        const u16* xc = c ? x1 : x0;
        const u32* pa0 = (const u32*)(xc + arow0 * 576 + (t - c) + quad * 8);
        const u32* pa1 = (const u32*)(xc + arow1 * 576 + (t - c) + quad * 8);
        #pragma unroll
        for (int s = 0; s < 16; ++s) {
          union { short8 v; u32 u[4]; } a0, a1;
          #pragma unroll
          for (int j = 0; j < 4; ++j) { a0.u[j] = pa0[s * 16 + j]; a1.u[j] = pa1[s * 16 + j]; }
          short8 br = wlds[(s)      * 64 + lane];
          short8 bz = wlds[(32 + s) * 64 + lane];
          short8 bi = wlds[(64 + s) * 64 + lane];
          acc[0][0] = MFMA(a0.v, br, acc[0][0], 0, 0, 0);
          acc[1][0] = MFMA(a1.v, br, acc[1][0], 0, 0, 0);
          acc[0][1] = MFMA(a0.v, bz, acc[0][1], 0, 0, 0);
          acc[1][1] = MFMA(a1.v, bz, acc[1][1], 0, 0, 0);
          acc[0][2] = MFMA(a0.v, bi, acc[0][2], 0, 0, 0);
          acc[1][2] = MFMA(a1.v, bi, acc[1][2], 0, 0, 0);
        }
      } else {
        const u16* h1c = h1b[cur];           // h1_new(p-1), produced last phase
        const short8* pa0 = (const short8*)(h1c + arow0 * 512 + quad * 8);
        const short8* pa1 = (const short8*)(h1c + arow1 * 512 + quad * 8);
        #pragma unroll
        for (int s = 0; s < 16; ++s) {
          short8 a0 = pa0[s * 4], a1 = pa1[s * 4];
          short8 br = wlds[(s)      * 64 + lane];
          short8 bz = wlds[(32 + s) * 64 + lane];
          short8 bi = wlds[(64 + s) * 64 + lane];
          acc[0][0] = MFMA(a0, br, acc[0][0], 0, 0, 0);
          acc[1][0] = MFMA(a1, br, acc[1][0], 0, 0, 0);
          acc[0][1] = MFMA(a0, bz, acc[0][1], 0, 0, 0);
          acc[1][1] = MFMA(a1, bz, acc[1][1], 0, 0, 0);
          acc[0][2] = MFMA(a0, bi, acc[0][2], 0, 0, 0);
          acc[1][2] = MFMA(a1, bi, acc[1][2], 0, 0, 0);
        }
      }
      // ---- K second half (own hidden operand): gates r, z, h_n ----
      {
        const u16* hown = layer ? h2b[cur] : h1b[cur];
        const short8* po0 = (const short8*)(hown + arow0 * 512 + quad * 8);
        const short8* po1 = (const short8*)(hown + arow1 * 512 + quad * 8);
        #pragma unroll
        for (int s = 0; s < 16; ++s) {
          short8 a0 = po0[s * 4], a1 = po1[s * 4];
          short8 br = wlds[(16 + s) * 64 + lane];
          short8 bz = wlds[(48 + s) * 64 + lane];
          short8 bh = wlds[(80 + s) * 64 + lane];
          acc[0][0] = MFMA(a0, br, acc[0][0], 0, 0, 0);
          acc[1][0] = MFMA(a1, br, acc[1][0], 0, 0, 0);
          acc[0][1] = MFMA(a0, bz, acc[0][1], 0, 0, 0);
          acc[1][1] = MFMA(a1, bz, acc[1][1], 0, 0, 0);
          acc[0][3] = MFMA(a0, bh, acc[0][3], 0, 0, 0);
          acc[1][3] = MFMA(a1, bh, acc[1][3], 0, 0, 0);
        }
      }
      // ---- gates + state update (C-layout: row = quad*4+q, col = m16) ----
      u16* hnxt = (layer ? h2b : h1b)[cur ^ 1];
      #pragma unroll
      for (int rf = 0; rf < 2; ++rf) {
        #pragma unroll
        for (int q = 0; q < 4; ++q) {
          float rg = sigm(acc[rf][0][q] + bias_r);
          float zg = sigm(acc[rf][1][q] + bias_z);
          float ng = tanhf(acc[rf][2][q] + bias_in + rg * (acc[rf][3][q] + bias_hn));
          float hv = (1.0f - zg) * ng + zg * hreg[rf][q];
          hreg[rf][q] = hv;
          int row = rb * 128 + (2 * w + rf) * 16 + quad * 4 + q;
          hnxt[row * 512 + nn] = f2bf(hv);
          if (layer) {
            float v = hv * wfc;                       // y partial over 16 cols
            v += __shfl_xor(v, 1);
            v += __shfl_xor(v, 2);
            v += __shfl_xor(v, 4);
            v += __shfl_xor(v, 8);
            if (m16 == 0) atomicAdd(&out[row * 64 + t], v + (n0 == 0 ? bfcv : 0.0f));
          }
        }
      }
    }
    RB_BARRIER();
  }

  // final hidden states straight from registers
  float* hout = out + 32768 + layer * (512 * 512);
  #pragma unroll
  for (int rf = 0; rf < 2; ++rf)
    #pragma unroll
    for (int q = 0; q < 4; ++q) {
      int row = rb * 128 + (2 * w + rf) * 16 + quad * 4 + q;
      hout[row * 512 + nn] = hreg[rf][q];
    }
}

extern "C" void kernel_launch(void* const* d_in, const int* in_sizes, int n_in,
                              void* d_out, int out_size, void* d_ws, size_t ws_size,
                              hipStream_t stream) {
  (void)in_sizes; (void)n_in; (void)out_size; (void)ws_size;
  // zero the y region (atomically accumulated) and the barrier counters
  hipMemsetAsync(d_out, 0, 32768 * sizeof(float), stream);
  hipMemsetAsync(d_ws, 0, 4096, stream);
  unsigned* bar = (unsigned*)d_ws;
  u16* wsb = (u16*)((char*)d_ws + 4096);
  gru_fused<<<256, 256, 0, stream>>>(
      (const float*)d_in[0], (const float*)d_in[1], (const float*)d_in[2],
      (const float*)d_in[3], (const float*)d_in[4], (const float*)d_in[5], (const float*)d_in[6],
      (const float*)d_in[7], (const float*)d_in[8], (const float*)d_in[9], (const float*)d_in[10],
      (const float*)d_in[11], (const float*)d_in[12],
      (float*)d_out, wsb, bar);
}

// Round 2
// 1337.297 us; speedup vs baseline: 1.0864x; 1.0864x over previous
//
#include <hip/hip_runtime.h>
#include <hip/hip_bf16.h>
#include <math.h>

typedef __attribute__((ext_vector_type(8))) short short8;
typedef __attribute__((ext_vector_type(4))) float f32x4;
typedef unsigned short u16;
typedef unsigned int u32;
typedef unsigned long long u64;

__device__ __forceinline__ u16 f2bf(float f) {
  union { float f; u32 u; } x; x.f = f;
  return (u16)((x.u + 0x7fffu + ((x.u >> 16) & 1u)) >> 16);
}
__device__ __forceinline__ float sigm(float v) { return 1.0f / (1.0f + __expf(-v)); }

#define MFMA __builtin_amdgcn_mfma_f32_16x16x32_bf16

// agent-scope (cache-coherent, write-through / L2-bypass) accessors for
// cross-WG h-state. Relaxed atomics compile to global_load/store with sc0/sc1
// set -> fine-grained coherence, NO cache-wide wbl2/inv fences needed.
__device__ __forceinline__ short8 ld_h16(const u16* p) {
  union { short8 v; u64 q[2]; } r;
  r.q[0] = __hip_atomic_load((const u64*)p,     __ATOMIC_RELAXED, __HIP_MEMORY_SCOPE_AGENT);
  r.q[1] = __hip_atomic_load((const u64*)p + 1, __ATOMIC_RELAXED, __HIP_MEMORY_SCOPE_AGENT);
  return r.v;
}
__device__ __forceinline__ void st_h2b(u16* p, u16 v) {
  __hip_atomic_store(p, v, __ATOMIC_RELAXED, __HIP_MEMORY_SCOPE_AGENT);
}
__device__ __forceinline__ void wait_ge(unsigned* c, unsigned target) {
  if (threadIdx.x == 0) {
    while (__hip_atomic_load(c, __ATOMIC_RELAXED, __HIP_MEMORY_SCOPE_AGENT) < target)
      __builtin_amdgcn_s_sleep(1);
  }
  __syncthreads();
}
__device__ __forceinline__ void arrive(unsigned* c) {
  __syncthreads();  // drains vmcnt: all write-through stores globally visible
  if (threadIdx.x == 0)
    __hip_atomic_fetch_add(c, 1u, __ATOMIC_RELAXED, __HIP_MEMORY_SCOPE_AGENT);
}

#define HS 262144  // 512*512 u16 per ring slot

// Persistent fused 2-layer GRU, decoupled producer/consumer pipeline.
// Grid: 256 WGs = 4 row-blocks x 2 layers x 32 col-blocks. bid&7 encodes
// (rb,layer) -> round-robin XCD mapping colocates each 32-WG group on one XCD.
// Layer-0 group produces h1(u) into a 4-deep ring; layer-1 trails, consuming
// h1(v) and producing h2(v)+y(v). Sync: per-group arrival counters only.
__global__ __launch_bounds__(256, 1) void gru_fused(
    const float* __restrict__ xin, const float* __restrict__ h1in, const float* __restrict__ h2in,
    const float* __restrict__ Wih1, const float* __restrict__ Whh1,
    const float* __restrict__ bih1, const float* __restrict__ bhh1,
    const float* __restrict__ Wih2, const float* __restrict__ Whh2,
    const float* __restrict__ bih2, const float* __restrict__ bhh2,
    const float* __restrict__ Wfc, const float* __restrict__ bfc,
    float* __restrict__ out, u16* __restrict__ wsb, unsigned* __restrict__ barc)
{
  const int bid   = blockIdx.x;
  const int rb    = bid & 3;
  const int layer = (bid >> 2) & 1;
  const int cbl   = bid >> 3;
  const int n0    = cbl * 16;
  const int wid   = bid >> 2;         // 0..63 unique within row-block
  const int tid   = threadIdx.x;
  const int w     = tid >> 6;
  const int lane  = tid & 63;
  const int quad  = lane >> 4;
  const int m16   = lane & 15;

  u16* x0  = wsb;                     // [512][576] bf16
  u16* x1  = x0 + 512 * 576;          // shifted copy
  u16* h1r = x1 + 512 * 576;          // 4-slot ring [4][512][512]
  u16* h2r = h1r + 4 * HS;            // 4-slot ring

  __shared__ short8 wlds[96 * 64];    // 96 KB weight fragments

  unsigned* c0    = barc + rb * 64;        // layer-0 arrivals (this rb)
  unsigned* c1    = c0 + 32;               // layer-1 arrivals
  unsigned* cinit = barc + 512;

  const float* Wih = layer ? Wih2 : Wih1;
  const float* Whh = layer ? Whh2 : Whh1;
  const float* bih = layer ? bih2 : bih1;
  const float* bhh = layer ? bhh2 : bhh1;

  // ---------------- one-time init (all scoped stores -> globally visible) ----------------
  for (int i = wid * 256 + tid; i < 128 * 575; i += 64 * 256) {
    int r = i / 575, c = i - r * 575;
    int row = rb * 128 + r;
    u16 bv = f2bf(xin[row * 575 + c]);
    st_h2b(&x0[row * 576 + c], bv);
    if (c >= 1) st_h2b(&x1[row * 576 + (c - 1)], bv);
  }
  // seeds: h1(-1) and h2(-1) live in slot 3
  for (int i = wid * 256 + tid; i < 128 * 512; i += 64 * 256) {
    int r = i >> 9, c = i & 511;
    int row = rb * 128 + r;
    st_h2b(&h1r[3 * HS + row * 512 + c], f2bf(h1in[row * 512 + c]));
    st_h2b(&h2r[3 * HS + row * 512 + c], f2bf(h2in[row * 512 + c]));
  }
  // weights -> LDS, B-fragment order: lane holds B[k = s*32 + quad*8 + j][n0 + m16]
  for (int i = tid; i < 96 * 64; i += 256) {
    int blk = i >> 6, l = i & 63;
    int s, gr;
    if (blk < 64) { s = blk & 31; gr = (blk >> 5) * 512; }   // r / z, full K
    else          { s = blk - 64; gr = 1024; }               // i_n (s<16) / h_n (s>=16)
    int n  = n0 + (l & 15);
    int k0 = s * 32 + (l >> 4) * 8;
    short8 pk;
    #pragma unroll
    for (int j = 0; j < 8; ++j) {
      int k = k0 + j;
      float v = (k < 512) ? Wih[(gr + n) * 512 + k] : Whh[(gr + n) * 512 + (k - 512)];
      pk[j] = (short)f2bf(v);
    }
    wlds[blk * 64 + l] = pk;
  }

  float hreg[2][4];
  const float* hin = layer ? h2in : h1in;
  #pragma unroll
  for (int rf = 0; rf < 2; ++rf)
    #pragma unroll
    for (int q = 0; q < 4; ++q)
      hreg[rf][q] = hin[(rb * 128 + (2 * w + rf) * 16 + quad * 4 + q) * 512 + n0 + m16];

  const int nn = n0 + m16;
  const float bias_r  = bih[nn] + bhh[nn];
  const float bias_z  = bih[512 + nn] + bhh[512 + nn];
  const float bias_in = bih[1024 + nn];
  const float bias_hn = bhh[1024 + nn];
  const float wfc  = Wfc[nn];
  const float bfcv = bfc[0];

  arrive(cinit);
  wait_ge(cinit, 256);

  const int arow0 = rb * 128 + (2 * w) * 16 + m16;
  const int arow1 = arow0 + 16;

  if (layer == 0) {
    // =================== producer: h1(u), u = 0..63 ===================
    for (int u = 0; u < 64; ++u) {
      f32x4 acc[2][4] = {};
      // ---- x-half (independent of peers -> overlaps their completion) ----
      {
        const int c = u & 1;
        const u16* xc = c ? x1 : x0;
        const u32* pa0 = (const u32*)(xc + (size_t)arow0 * 576 + (u - c) + quad * 8);
        const u32* pa1 = (const u32*)(xc + (size_t)arow1 * 576 + (u - c) + quad * 8);
        #pragma unroll
        for (int s = 0; s < 16; ++s) {
          union { short8 v; u32 u4[4]; } a0, a1;
          #pragma unroll
          for (int j = 0; j < 4; ++j) { a0.u4[j] = pa0[s * 16 + j]; a1.u4[j] = pa1[s * 16 + j]; }
          short8 br = wlds[(s)      * 64 + lane];
          short8 bz = wlds[(32 + s) * 64 + lane];
          short8 bi = wlds[(64 + s) * 64 + lane];
          acc[0][0] = MFMA(a0.v, br, acc[0][0], 0, 0, 0);
          acc[1][0] = MFMA(a1.v, br, acc[1][0], 0, 0, 0);
          acc[0][1] = MFMA(a0.v, bz, acc[0][1], 0, 0, 0);
          acc[1][1] = MFMA(a1.v, bz, acc[1][1], 0, 0, 0);
          acc[0][2] = MFMA(a0.v, bi, acc[0][2], 0, 0, 0);
          acc[1][2] = MFMA(a1.v, bi, acc[1][2], 0, 0, 0);
        }
      }
      // ---- wait: peers produced h1(u-1) ----
      wait_ge(c0, 32u * (unsigned)u);
      // ---- h-half: own-hidden operand, chunked scoped loads ----
      {
        const u16* hp0 = h1r + (size_t)((u + 3) & 3) * HS + (size_t)arow0 * 512 + quad * 8;
        const u16* hp1 = hp0 + 16 * 512;
        #pragma unroll
        for (int sc = 0; sc < 4; ++sc) {
          short8 a0[4], a1[4];
          #pragma unroll
          for (int j = 0; j < 4; ++j) {
            a0[j] = ld_h16(hp0 + (sc * 4 + j) * 32);
            a1[j] = ld_h16(hp1 + (sc * 4 + j) * 32);
          }
          #pragma unroll
          for (int j = 0; j < 4; ++j) {
            int s = sc * 4 + j;
            short8 br = wlds[(16 + s) * 64 + lane];
            short8 bz = wlds[(48 + s) * 64 + lane];
            short8 bh = wlds[(80 + s) * 64 + lane];
            acc[0][0] = MFMA(a0[j], br, acc[0][0], 0, 0, 0);
            acc[1][0] = MFMA(a1[j], br, acc[1][0], 0, 0, 0);
            acc[0][1] = MFMA(a0[j], bz, acc[0][1], 0, 0, 0);
            acc[1][1] = MFMA(a1[j], bz, acc[1][1], 0, 0, 0);
            acc[0][3] = MFMA(a0[j], bh, acc[0][3], 0, 0, 0);
            acc[1][3] = MFMA(a1[j], bh, acc[1][3], 0, 0, 0);
          }
        }
      }
      // ---- gates ----
      #pragma unroll
      for (int rf = 0; rf < 2; ++rf)
        #pragma unroll
        for (int q = 0; q < 4; ++q) {
          float rg = sigm(acc[rf][0][q] + bias_r);
          float zg = sigm(acc[rf][1][q] + bias_z);
          float ng = tanhf(acc[rf][2][q] + bias_in + rg * (acc[rf][3][q] + bias_hn));
          hreg[rf][q] = (1.0f - zg) * ng + zg * hreg[rf][q];
        }
      // ---- ring reuse guard: layer-1 done reading h1(u-4) ----
      wait_ge(c1, u >= 4 ? 32u * (unsigned)(u - 3) : 0u);
      // ---- publish h1(u) ----
      {
        u16* hw = h1r + (size_t)(u & 3) * HS;
        #pragma unroll
        for (int rf = 0; rf < 2; ++rf)
          #pragma unroll
          for (int q = 0; q < 4; ++q) {
            int row = rb * 128 + (2 * w + rf) * 16 + quad * 4 + q;
            st_h2b(&hw[row * 512 + nn], f2bf(hreg[rf][q]));
          }
      }
      arrive(c0);
    }
  } else {
    // =================== consumer: h2(v) + y(v), v = 0..63 ===================
    for (int v = 0; v < 64; ++v) {
      f32x4 acc[2][4] = {};
      // ---- wait: own peers produced h2(v-1); then own-hidden half ----
      wait_ge(c1, 32u * (unsigned)v);
      {
        const u16* hp0 = h2r + (size_t)((v + 3) & 3) * HS + (size_t)arow0 * 512 + quad * 8;
        const u16* hp1 = hp0 + 16 * 512;
        #pragma unroll
        for (int sc = 0; sc < 4; ++sc) {
          short8 a0[4], a1[4];
          #pragma unroll
          for (int j = 0; j < 4; ++j) {
            a0[j] = ld_h16(hp0 + (sc * 4 + j) * 32);
            a1[j] = ld_h16(hp1 + (sc * 4 + j) * 32);
          }
          #pragma unroll
          for (int j = 0; j < 4; ++j) {
            int s = sc * 4 + j;
            short8 br = wlds[(16 + s) * 64 + lane];
            short8 bz = wlds[(48 + s) * 64 + lane];
            short8 bh = wlds[(80 + s) * 64 + lane];
            acc[0][0] = MFMA(a0[j], br, acc[0][0], 0, 0, 0);
            acc[1][0] = MFMA(a1[j], br, acc[1][0], 0, 0, 0);
            acc[0][1] = MFMA(a0[j], bz, acc[0][1], 0, 0, 0);
            acc[1][1] = MFMA(a1[j], bz, acc[1][1], 0, 0, 0);
            acc[0][3] = MFMA(a0[j], bh, acc[0][3], 0, 0, 0);
            acc[1][3] = MFMA(a1[j], bh, acc[1][3], 0, 0, 0);
          }
        }
      }
      // ---- wait: layer-0 produced h1(v) (usually already satisfied) ----
      wait_ge(c0, 32u * (unsigned)(v + 1));
      {
        const u16* hp0 = h1r + (size_t)(v & 3) * HS + (size_t)arow0 * 512 + quad * 8;
        const u16* hp1 = hp0 + 16 * 512;
        #pragma unroll
        for (int sc = 0; sc < 4; ++sc) {
          short8 a0[4], a1[4];
          #pragma unroll
          for (int j = 0; j < 4; ++j) {
            a0[j] = ld_h16(hp0 + (sc * 4 + j) * 32);
            a1[j] = ld_h16(hp1 + (sc * 4 + j) * 32);
          }
          #pragma unroll
          for (int j = 0; j < 4; ++j) {
            int s = sc * 4 + j;
            short8 br = wlds[(s)      * 64 + lane];
            short8 bz = wlds[(32 + s) * 64 + lane];
            short8 bi = wlds[(64 + s) * 64 + lane];
            acc[0][0] = MFMA(a0[j], br, acc[0][0], 0, 0, 0);
            acc[1][0] = MFMA(a1[j], br, acc[1][0], 0, 0, 0);
            acc[0][1] = MFMA(a0[j], bz, acc[0][1], 0, 0, 0);
            acc[1][1] = MFMA(a1[j], bz, acc[1][1], 0, 0, 0);
            acc[0][2] = MFMA(a0[j], bi, acc[0][2], 0, 0, 0);
            acc[1][2] = MFMA(a1[j], bi, acc[1][2], 0, 0, 0);
          }
        }
      }
      // ---- gates + y + publish h2(v) ----
      {
        u16* hw = h2r + (size_t)(v & 3) * HS;
        #pragma unroll
        for (int rf = 0; rf < 2; ++rf)
          #pragma unroll
          for (int q = 0; q < 4; ++q) {
            float rg = sigm(acc[rf][0][q] + bias_r);
            float zg = sigm(acc[rf][1][q] + bias_z);
            float ng = tanhf(acc[rf][2][q] + bias_in + rg * (acc[rf][3][q] + bias_hn));
            float hv = (1.0f - zg) * ng + zg * hreg[rf][q];
            hreg[rf][q] = hv;
            int row = rb * 128 + (2 * w + rf) * 16 + quad * 4 + q;
            st_h2b(&hw[row * 512 + nn], f2bf(hv));
            float yv = hv * wfc;
            yv += __shfl_xor(yv, 1);
            yv += __shfl_xor(yv, 2);
            yv += __shfl_xor(yv, 4);
            yv += __shfl_xor(yv, 8);
            if (m16 == 0) atomicAdd(&out[row * 64 + v], yv + (n0 == 0 ? bfcv : 0.0f));
          }
      }
      arrive(c1);
    }
  }

  // final hidden states from registers (fp32 exact)
  float* hout = out + 32768 + layer * (512 * 512);
  #pragma unroll
  for (int rf = 0; rf < 2; ++rf)
    #pragma unroll
    for (int q = 0; q < 4; ++q) {
      int row = rb * 128 + (2 * w + rf) * 16 + quad * 4 + q;
      hout[row * 512 + nn] = hreg[rf][q];
    }
}

extern "C" void kernel_launch(void* const* d_in, const int* in_sizes, int n_in,
                              void* d_out, int out_size, void* d_ws, size_t ws_size,
                              hipStream_t stream) {
  (void)in_sizes; (void)n_in; (void)out_size; (void)ws_size;
  hipMemsetAsync(d_out, 0, 32768 * sizeof(float), stream);   // y accumulators
  hipMemsetAsync(d_ws, 0, 4096, stream);                     // arrival counters
  unsigned* bar = (unsigned*)d_ws;
  u16* wsb = (u16*)((char*)d_ws + 4096);
  gru_fused<<<256, 256, 0, stream>>>(
      (const float*)d_in[0], (const float*)d_in[1], (const float*)d_in[2],
      (const float*)d_in[3], (const float*)d_in[4], (const float*)d_in[5], (const float*)d_in[6],
      (const float*)d_in[7], (const float*)d_in[8], (const float*)d_in[9], (const float*)d_in[10],
      (const float*)d_in[11], (const float*)d_in[12],
      (float*)d_out, wsb, bar);
}

// Round 3
// 1119.761 us; speedup vs baseline: 1.2975x; 1.1943x over previous
//
#include <hip/hip_runtime.h>
#include <hip/hip_bf16.h>
#include <math.h>

typedef __attribute__((ext_vector_type(8))) short short8;
typedef __attribute__((ext_vector_type(4))) float f32x4;
typedef unsigned short u16;
typedef unsigned int u32;

__device__ __forceinline__ u16 f2bf(float f) {
  union { float f; u32 u; } x; x.f = f;
  return (u16)((x.u + 0x7fffu + ((x.u >> 16) & 1u)) >> 16);
}
__device__ __forceinline__ float sigm(float v) { return 1.0f / (1.0f + __expf(-v)); }

#define MFMA __builtin_amdgcn_mfma_f32_16x16x32_bf16
#define HS 262144  // 512*512 u16 per ring slot

// Consumer wait: relaxed poll on up to two counters, then ONE acquire fence
// (buffer_inv: drops clean L2 lines -> next plain loads refetch fresh data
// from MALL once; dirty lines survive). __syncthreads orders peers after inv.
__device__ __forceinline__ void waits(unsigned* a, unsigned ta, unsigned* b, unsigned tb) {
  if (threadIdx.x == 0) {
    while (__hip_atomic_load(a, __ATOMIC_RELAXED, __HIP_MEMORY_SCOPE_AGENT) < ta)
      __builtin_amdgcn_s_sleep(1);
    while (__hip_atomic_load(b, __ATOMIC_RELAXED, __HIP_MEMORY_SCOPE_AGENT) < tb)
      __builtin_amdgcn_s_sleep(1);
    __builtin_amdgcn_fence(__ATOMIC_ACQUIRE, "agent");
  }
  __syncthreads();
}
// Producer arrive: syncthreads drains all threads' stores to L2 (vmcnt(0)
// before s_barrier), then ONE release fence (buffer_wbl2: write back dirty L2
// to MALL) + relaxed counter increment.
__device__ __forceinline__ void arrive_rel(unsigned* c) {
  __syncthreads();
  if (threadIdx.x == 0) {
    __builtin_amdgcn_fence(__ATOMIC_RELEASE, "agent");
    __hip_atomic_fetch_add(c, 1u, __ATOMIC_RELAXED, __HIP_MEMORY_SCOPE_AGENT);
  }
}

// Persistent fused 2-layer GRU, decoupled producer/consumer pipeline.
// Grid: 256 WGs = 4 row-blocks x 2 layers x 32 col-blocks; bid&7 -> XCD
// round-robin colocates each 32-WG (rb,layer) group on one XCD, so h-state
// replication (32 WGs x 128KB/step) is served from that XCD's L2; only the
// once-per-step handoff crosses through the MALL via wbl2/inv fences.
__global__ __launch_bounds__(256, 1) void gru_fused(
    const float* __restrict__ xin, const float* __restrict__ h1in, const float* __restrict__ h2in,
    const float* __restrict__ Wih1, const float* __restrict__ Whh1,
    const float* __restrict__ bih1, const float* __restrict__ bhh1,
    const float* __restrict__ Wih2, const float* __restrict__ Whh2,
    const float* __restrict__ bih2, const float* __restrict__ bhh2,
    const float* __restrict__ Wfc, const float* __restrict__ bfc,
    float* __restrict__ out, u16* __restrict__ wsb, unsigned* __restrict__ barc)
{
  const int bid   = blockIdx.x;
  const int rb    = bid & 3;
  const int layer = (bid >> 2) & 1;
  const int cbl   = bid >> 3;
  const int n0    = cbl * 16;
  const int wid   = bid >> 2;         // 0..63 unique within row-block
  const int tid   = threadIdx.x;
  const int w     = tid >> 6;
  const int lane  = tid & 63;
  const int quad  = lane >> 4;
  const int m16   = lane & 15;

  u16* x0  = wsb;                     // [512][576] bf16
  u16* x1  = x0 + 512 * 576;          // shifted copy (odd-t alignment)
  u16* h1r = x1 + 512 * 576;          // 4-slot ring [4][512][512]
  u16* h2r = h1r + 4 * HS;            // 4-slot ring

  __shared__ short8 wlds[96 * 64];    // 96 KB weight fragments

  unsigned* c0    = barc + rb * 32;         // layer-0 arrivals (this rb)
  unsigned* c1    = barc + 256 + rb * 32;   // layer-1 arrivals
  unsigned* cinit = barc + 512;

  const float* Wih = layer ? Wih2 : Wih1;
  const float* Whh = layer ? Whh2 : Whh1;
  const float* bih = layer ? bih2 : bih1;
  const float* bhh = layer ? bhh2 : bhh1;

  // ---------------- one-time init (plain stores; flushed by init release) ----------------
  for (int i = wid * 256 + tid; i < 128 * 575; i += 64 * 256) {
    int r = i / 575, c = i - r * 575;
    int row = rb * 128 + r;
    u16 bv = f2bf(xin[row * 575 + c]);
    x0[row * 576 + c] = bv;
    if (c >= 1) x1[row * 576 + (c - 1)] = bv;
  }
  // seeds: h1(-1) and h2(-1) live in slot 3
  for (int i = wid * 256 + tid; i < 128 * 512; i += 64 * 256) {
    int r = i >> 9, c = i & 511;
    int row = rb * 128 + r;
    h1r[3 * HS + row * 512 + c] = f2bf(h1in[row * 512 + c]);
    h2r[3 * HS + row * 512 + c] = f2bf(h2in[row * 512 + c]);
  }
  // weights -> LDS, B-fragment order: lane holds B[k = s*32 + quad*8 + j][n0 + m16]
  for (int i = tid; i < 96 * 64; i += 256) {
    int blk = i >> 6, l = i & 63;
    int s, gr;
    if (blk < 64) { s = blk & 31; gr = (blk >> 5) * 512; }   // r / z, full K
    else          { s = blk - 64; gr = 1024; }               // i_n (s<16) / h_n (s>=16)
    int n  = n0 + (l & 15);
    int k0 = s * 32 + (l >> 4) * 8;
    short8 pk;
    #pragma unroll
    for (int j = 0; j < 8; ++j) {
      int k = k0 + j;
      float v = (k < 512) ? Wih[(gr + n) * 512 + k] : Whh[(gr + n) * 512 + (k - 512)];
      pk[j] = (short)f2bf(v);
    }
    wlds[blk * 64 + l] = pk;
  }

  float hreg[2][4];
  const float* hin = layer ? h2in : h1in;
  #pragma unroll
  for (int rf = 0; rf < 2; ++rf)
    #pragma unroll
    for (int q = 0; q < 4; ++q)
      hreg[rf][q] = hin[(rb * 128 + (2 * w + rf) * 16 + quad * 4 + q) * 512 + n0 + m16];

  const int nn = n0 + m16;
  const float bias_r  = bih[nn] + bhh[nn];
  const float bias_z  = bih[512 + nn] + bhh[512 + nn];
  const float bias_in = bih[1024 + nn];
  const float bias_hn = bhh[1024 + nn];
  const float wfc  = Wfc[nn];
  const float bfcv = bfc[0];

  // init barrier: release own stores, wait all 256, acquire
  __syncthreads();
  if (tid == 0) {
    __builtin_amdgcn_fence(__ATOMIC_RELEASE, "agent");
    __hip_atomic_fetch_add(cinit, 1u, __ATOMIC_RELAXED, __HIP_MEMORY_SCOPE_AGENT);
    while (__hip_atomic_load(cinit, __ATOMIC_RELAXED, __HIP_MEMORY_SCOPE_AGENT) < 256u)
      __builtin_amdgcn_s_sleep(1);
    __builtin_amdgcn_fence(__ATOMIC_ACQUIRE, "agent");
  }
  __syncthreads();

  const int arow0 = rb * 128 + (2 * w) * 16 + m16;
  const int arow1 = arow0 + 16;

  if (layer == 0) {
    // =================== producer: h1(u), u = 0..63 ===================
    for (int u = 0; u < 64; ++u) {
      f32x4 acc[2][4] = {};
      // ---- x-half (no peer dependency; overlaps peers finishing u-1) ----
      {
        const int c = u & 1;
        const u16* xc = c ? x1 : x0;
        const u32* pa0 = (const u32*)(xc + (size_t)arow0 * 576 + (u - c) + quad * 8);
        const u32* pa1 = (const u32*)(xc + (size_t)arow1 * 576 + (u - c) + quad * 8);
        #pragma unroll
        for (int s = 0; s < 16; ++s) {
          union { short8 v; u32 u4[4]; } a0, a1;
          #pragma unroll
          for (int j = 0; j < 4; ++j) { a0.u4[j] = pa0[s * 16 + j]; a1.u4[j] = pa1[s * 16 + j]; }
          short8 br = wlds[(s)      * 64 + lane];
          short8 bz = wlds[(32 + s) * 64 + lane];
          short8 bi = wlds[(64 + s) * 64 + lane];
          acc[0][0] = MFMA(a0.v, br, acc[0][0], 0, 0, 0);
          acc[1][0] = MFMA(a1.v, br, acc[1][0], 0, 0, 0);
          acc[0][1] = MFMA(a0.v, bz, acc[0][1], 0, 0, 0);
          acc[1][1] = MFMA(a1.v, bz, acc[1][1], 0, 0, 0);
          acc[0][2] = MFMA(a0.v, bi, acc[0][2], 0, 0, 0);
          acc[1][2] = MFMA(a1.v, bi, acc[1][2], 0, 0, 0);
        }
      }
      // ---- wait: peers h1(u-1) ready; ring slot u&3 free (layer-1 past u-4) ----
      waits(c0, 32u * (unsigned)u, c1, u >= 4 ? 32u * (unsigned)(u - 3) : 0u);
      // ---- h-half: plain coalesced loads from L2 ----
      {
        const short8* hp0 = (const short8*)(h1r + (size_t)((u + 3) & 3) * HS + (size_t)arow0 * 512 + quad * 8);
        const short8* hp1 = (const short8*)(h1r + (size_t)((u + 3) & 3) * HS + (size_t)arow1 * 512 + quad * 8);
        #pragma unroll
        for (int sc = 0; sc < 4; ++sc) {
          short8 a0[4], a1[4];
          #pragma unroll
          for (int j = 0; j < 4; ++j) {
            a0[j] = hp0[(sc * 4 + j) * 4];
            a1[j] = hp1[(sc * 4 + j) * 4];
          }
          #pragma unroll
          for (int j = 0; j < 4; ++j) {
            int s = sc * 4 + j;
            short8 br = wlds[(16 + s) * 64 + lane];
            short8 bz = wlds[(48 + s) * 64 + lane];
            short8 bh = wlds[(80 + s) * 64 + lane];
            acc[0][0] = MFMA(a0[j], br, acc[0][0], 0, 0, 0);
            acc[1][0] = MFMA(a1[j], br, acc[1][0], 0, 0, 0);
            acc[0][1] = MFMA(a0[j], bz, acc[0][1], 0, 0, 0);
            acc[1][1] = MFMA(a1[j], bz, acc[1][1], 0, 0, 0);
            acc[0][3] = MFMA(a0[j], bh, acc[0][3], 0, 0, 0);
            acc[1][3] = MFMA(a1[j], bh, acc[1][3], 0, 0, 0);
          }
        }
      }
      // ---- gates + publish h1(u) ----
      u16* hw = h1r + (size_t)(u & 3) * HS;
      #pragma unroll
      for (int rf = 0; rf < 2; ++rf)
        #pragma unroll
        for (int q = 0; q < 4; ++q) {
          float rg = sigm(acc[rf][0][q] + bias_r);
          float zg = sigm(acc[rf][1][q] + bias_z);
          float ng = tanhf(acc[rf][2][q] + bias_in + rg * (acc[rf][3][q] + bias_hn));
          float hv = (1.0f - zg) * ng + zg * hreg[rf][q];
          hreg[rf][q] = hv;
          int row = rb * 128 + (2 * w + rf) * 16 + quad * 4 + q;
          hw[row * 512 + nn] = f2bf(hv);
        }
      arrive_rel(c0);
    }
  } else {
    // =================== consumer: h2(v) + y(v), v = 0..63 ===================
    for (int v = 0; v < 64; ++v) {
      f32x4 acc[2][4] = {};
      // ---- one wait for both deps: peers h2(v-1), layer-0 h1(v) ----
      waits(c1, 32u * (unsigned)v, c0, 32u * (unsigned)(v + 1));
      // ---- h1-half (input operand): gates r, z, i_n ----
      {
        const short8* hp0 = (const short8*)(h1r + (size_t)(v & 3) * HS + (size_t)arow0 * 512 + quad * 8);
        const short8* hp1 = (const short8*)(h1r + (size_t)(v & 3) * HS + (size_t)arow1 * 512 + quad * 8);
        #pragma unroll
        for (int sc = 0; sc < 4; ++sc) {
          short8 a0[4], a1[4];
          #pragma unroll
          for (int j = 0; j < 4; ++j) {
            a0[j] = hp0[(sc * 4 + j) * 4];
            a1[j] = hp1[(sc * 4 + j) * 4];
          }
          #pragma unroll
          for (int j = 0; j < 4; ++j) {
            int s = sc * 4 + j;
            short8 br = wlds[(s)      * 64 + lane];
            short8 bz = wlds[(32 + s) * 64 + lane];
            short8 bi = wlds[(64 + s) * 64 + lane];
            acc[0][0] = MFMA(a0[j], br, acc[0][0], 0, 0, 0);
            acc[1][0] = MFMA(a1[j], br, acc[1][0], 0, 0, 0);
            acc[0][1] = MFMA(a0[j], bz, acc[0][1], 0, 0, 0);
            acc[1][1] = MFMA(a1[j], bz, acc[1][1], 0, 0, 0);
            acc[0][2] = MFMA(a0[j], bi, acc[0][2], 0, 0, 0);
            acc[1][2] = MFMA(a1[j], bi, acc[1][2], 0, 0, 0);
          }
        }
      }
      // ---- h2-half (own recurrence): gates r, z, h_n ----
      {
        const short8* hp0 = (const short8*)(h2r + (size_t)((v + 3) & 3) * HS + (size_t)arow0 * 512 + quad * 8);
        const short8* hp1 = (const short8*)(h2r + (size_t)((v + 3) & 3) * HS + (size_t)arow1 * 512 + quad * 8);
        #pragma unroll
        for (int sc = 0; sc < 4; ++sc) {
          short8 a0[4], a1[4];
          #pragma unroll
          for (int j = 0; j < 4; ++j) {
            a0[j] = hp0[(sc * 4 + j) * 4];
            a1[j] = hp1[(sc * 4 + j) * 4];
          }
          #pragma unroll
          for (int j = 0; j < 4; ++j) {
            int s = sc * 4 + j;
            short8 br = wlds[(16 + s) * 64 + lane];
            short8 bz = wlds[(48 + s) * 64 + lane];
            short8 bh = wlds[(80 + s) * 64 + lane];
            acc[0][0] = MFMA(a0[j], br, acc[0][0], 0, 0, 0);
            acc[1][0] = MFMA(a1[j], br, acc[1][0], 0, 0, 0);
            acc[0][1] = MFMA(a0[j], bz, acc[0][1], 0, 0, 0);
            acc[1][1] = MFMA(a1[j], bz, acc[1][1], 0, 0, 0);
            acc[0][3] = MFMA(a0[j], bh, acc[0][3], 0, 0, 0);
            acc[1][3] = MFMA(a1[j], bh, acc[1][3], 0, 0, 0);
          }
        }
      }
      // ---- gates + publish h2(v) ----
      u16* hw = h2r + (size_t)(v & 3) * HS;
      #pragma unroll
      for (int rf = 0; rf < 2; ++rf)
        #pragma unroll
        for (int q = 0; q < 4; ++q) {
          float rg = sigm(acc[rf][0][q] + bias_r);
          float zg = sigm(acc[rf][1][q] + bias_z);
          float ng = tanhf(acc[rf][2][q] + bias_in + rg * (acc[rf][3][q] + bias_hn));
          float hv = (1.0f - zg) * ng + zg * hreg[rf][q];
          hreg[rf][q] = hv;
          int row = rb * 128 + (2 * w + rf) * 16 + quad * 4 + q;
          hw[row * 512 + nn] = f2bf(hv);
        }
      arrive_rel(c1);
      // ---- y after arrive: atomics drain overlapped with next poll ----
      #pragma unroll
      for (int rf = 0; rf < 2; ++rf)
        #pragma unroll
        for (int q = 0; q < 4; ++q) {
          float yv = hreg[rf][q] * wfc;
          yv += __shfl_xor(yv, 1);
          yv += __shfl_xor(yv, 2);
          yv += __shfl_xor(yv, 4);
          yv += __shfl_xor(yv, 8);
          if (m16 == 0) {
            int row = rb * 128 + (2 * w + rf) * 16 + quad * 4 + q;
            atomicAdd(&out[row * 64 + v], yv + (n0 == 0 ? bfcv : 0.0f));
          }
        }
    }
  }

  // final hidden states from registers (fp32 exact)
  float* hout = out + 32768 + layer * (512 * 512);
  #pragma unroll
  for (int rf = 0; rf < 2; ++rf)
    #pragma unroll
    for (int q = 0; q < 4; ++q) {
      int row = rb * 128 + (2 * w + rf) * 16 + quad * 4 + q;
      hout[row * 512 + nn] = hreg[rf][q];
    }
}

extern "C" void kernel_launch(void* const* d_in, const int* in_sizes, int n_in,
                              void* d_out, int out_size, void* d_ws, size_t ws_size,
                              hipStream_t stream) {
  (void)in_sizes; (void)n_in; (void)out_size; (void)ws_size;
  hipMemsetAsync(d_out, 0, 32768 * sizeof(float), stream);   // y accumulators
  hipMemsetAsync(d_ws, 0, 4096, stream);                     // arrival counters
  unsigned* bar = (unsigned*)d_ws;
  u16* wsb = (u16*)((char*)d_ws + 4096);
  gru_fused<<<256, 256, 0, stream>>>(
      (const float*)d_in[0], (const float*)d_in[1], (const float*)d_in[2],
      (const float*)d_in[3], (const float*)d_in[4], (const float*)d_in[5], (const float*)d_in[6],
      (const float*)d_in[7], (const float*)d_in[8], (const float*)d_in[9], (const float*)d_in[10],
      (const float*)d_in[11], (const float*)d_in[12],
      (float*)d_out, wsb, bar);
}

// Round 5
// 806.764 us; speedup vs baseline: 1.8009x; 1.3880x over previous
//
#include <hip/hip_runtime.h>
#include <hip/hip_bf16.h>
#include <math.h>

typedef __attribute__((ext_vector_type(8))) short short8;
typedef __attribute__((ext_vector_type(4))) float f32x4;
typedef unsigned short u16;
typedef unsigned int u32;

__device__ __forceinline__ u16 f2bf(float f) {
  union { float f; u32 u; } x; x.f = f;
  return (u16)((x.u + 0x7fffu + ((x.u >> 16) & 1u)) >> 16);
}
__device__ __forceinline__ float sigm(float v) { return 1.0f / (1.0f + __expf(-v)); }

#define MFMA __builtin_amdgcn_mfma_f32_16x16x32_bf16
#define HS 262144  // 512*512 u16 per ring slot

// 16 x 16B loads (stride 64B) in one asm block, single latency exposure.
// NOTE gfx950 asm modifier order: `off offset:N sc0 [sc1]` (flags AFTER offset).
// sc0: bypass L1, served by local XCD L2 (fresh for same-XCD producer/consumer).
#define LDG16_BODY(FL)                                        \
    "global_load_dwordx4 %0, %16, off " FL "\n\t"             \
    "global_load_dwordx4 %1, %16, off offset:64 " FL "\n\t"   \
    "global_load_dwordx4 %2, %16, off offset:128 " FL "\n\t"  \
    "global_load_dwordx4 %3, %16, off offset:192 " FL "\n\t"  \
    "global_load_dwordx4 %4, %16, off offset:256 " FL "\n\t"  \
    "global_load_dwordx4 %5, %16, off offset:320 " FL "\n\t"  \
    "global_load_dwordx4 %6, %16, off offset:384 " FL "\n\t"  \
    "global_load_dwordx4 %7, %16, off offset:448 " FL "\n\t"  \
    "global_load_dwordx4 %8, %16, off offset:512 " FL "\n\t"  \
    "global_load_dwordx4 %9, %16, off offset:576 " FL "\n\t"  \
    "global_load_dwordx4 %10, %16, off offset:640 " FL "\n\t" \
    "global_load_dwordx4 %11, %16, off offset:704 " FL "\n\t" \
    "global_load_dwordx4 %12, %16, off offset:768 " FL "\n\t" \
    "global_load_dwordx4 %13, %16, off offset:832 " FL "\n\t" \
    "global_load_dwordx4 %14, %16, off offset:896 " FL "\n\t" \
    "global_load_dwordx4 %15, %16, off offset:960 " FL "\n\t" \
    "s_waitcnt vmcnt(0)"
#define LDG16_OPS(a, base)                                                     \
    : "=&v"(a[0]), "=&v"(a[1]), "=&v"(a[2]), "=&v"(a[3]), "=&v"(a[4]),         \
      "=&v"(a[5]), "=&v"(a[6]), "=&v"(a[7]), "=&v"(a[8]), "=&v"(a[9]),         \
      "=&v"(a[10]), "=&v"(a[11]), "=&v"(a[12]), "=&v"(a[13]), "=&v"(a[14]),    \
      "=&v"(a[15])                                                             \
    : "v"(base) : "memory"

__device__ __forceinline__ void ldg16_sc0(short8 a[16], const u16* base) {
  asm volatile(LDG16_BODY("sc0") LDG16_OPS(a, base));
}
__device__ __forceinline__ void ldg16_sc01(short8 a[16], const u16* base) {
  asm volatile(LDG16_BODY("sc0 sc1") LDG16_OPS(a, base));
}
// MALL-direct store for the cross-XCD mirror copy.
__device__ __forceinline__ void stg_sc01(u32* p, u32 v) {
  asm volatile("global_store_dword %0, %1, off sc0 sc1" :: "v"(p), "v"(v) : "memory");
}

// Poll two counters (MALL-resident, agent atomics), then workgroup barrier.
// NO cache fences: data freshness is guaranteed by sc-bit discipline.
__device__ __forceinline__ void waits_nf(unsigned* a, unsigned ta, unsigned* b, unsigned tb) {
  if (threadIdx.x == 0) {
    while (__hip_atomic_load(a, __ATOMIC_RELAXED, __HIP_MEMORY_SCOPE_AGENT) < ta)
      __builtin_amdgcn_s_sleep(1);
    while (__hip_atomic_load(b, __ATOMIC_RELAXED, __HIP_MEMORY_SCOPE_AGENT) < tb)
      __builtin_amdgcn_s_sleep(1);
  }
  __syncthreads();
}

// Persistent fused 2-layer GRU, decoupled pipeline, ZERO steady-state fences.
// 256 WGs = 4 row-blocks x 2 layers x 32 col-blocks (1 WG/CU, all co-resident).
// Own-recurrence h: plain stores -> local L2 dirty; sc0 loads (L1-bypass).
// Cross-XCD h1 handoff: sc0sc1 mirror stores -> MALL; sc0sc1 loads <- MALL.
__global__ __launch_bounds__(256, 1) void gru_fused(
    const float* __restrict__ xin, const float* __restrict__ h1in, const float* __restrict__ h2in,
    const float* __restrict__ Wih1, const float* __restrict__ Whh1,
    const float* __restrict__ bih1, const float* __restrict__ bhh1,
    const float* __restrict__ Wih2, const float* __restrict__ Whh2,
    const float* __restrict__ bih2, const float* __restrict__ bhh2,
    const float* __restrict__ Wfc, const float* __restrict__ bfc,
    float* __restrict__ out, u16* __restrict__ wsb, unsigned* __restrict__ barc)
{
  const int bid   = blockIdx.x;
  const int rb    = bid & 3;
  const int layer = (bid >> 2) & 1;
  const int cbl   = bid >> 3;
  const int n0    = cbl * 16;
  const int wid   = bid >> 2;
  const int tid   = threadIdx.x;
  const int w     = tid >> 6;
  const int lane  = tid & 63;
  const int quad  = lane >> 4;
  const int m16   = lane & 15;

  u16* x0  = wsb;                     // [512][576] bf16 (immutable after init)
  u16* x1  = x0 + 512 * 576;          // shifted copy
  u16* h1r = x1 + 512 * 576;          // 4-slot ring, local to layer-0 XCDs
  u16* h2r = h1r + 4 * HS;            // 4-slot ring, local to layer-1 XCDs
  u16* h1m = h2r + 4 * HS;            // 4-slot MALL mirror of h1 (cross-XCD)

  __shared__ short8 wlds[96 * 64];    // 96 KB weight fragments

  unsigned* c0    = barc + rb * 32;
  unsigned* c1    = barc + 256 + rb * 32;
  unsigned* cinit = barc + 512;

  const float* Wih = layer ? Wih2 : Wih1;
  const float* Whh = layer ? Whh2 : Whh1;
  const float* bih = layer ? bih2 : bih1;
  const float* bhh = layer ? bhh2 : bhh1;

  // ---------------- one-time init ----------------
  for (int i = wid * 256 + tid; i < 128 * 575; i += 64 * 256) {
    int r = i / 575, c = i - r * 575;
    int row = rb * 128 + r;
    u16 bv = f2bf(xin[row * 575 + c]);
    x0[row * 576 + c] = bv;
    if (c >= 1) x1[row * 576 + (c - 1)] = bv;
  }
  for (int i = wid * 256 + tid; i < 128 * 512; i += 64 * 256) {
    int r = i >> 9, c = i & 511;
    int row = rb * 128 + r;
    u16 h1v = f2bf(h1in[row * 512 + c]);
    h1r[3 * HS + row * 512 + c] = h1v;
    h2r[3 * HS + row * 512 + c] = f2bf(h2in[row * 512 + c]);
  }
  for (int i = tid; i < 96 * 64; i += 256) {
    int blk = i >> 6, l = i & 63;
    int s, gr;
    if (blk < 64) { s = blk & 31; gr = (blk >> 5) * 512; }   // r / z, K=1024
    else          { s = blk - 64; gr = 1024; }               // i_n (s<16) / h_n (s>=16)
    int n  = n0 + (l & 15);
    int k0 = s * 32 + (l >> 4) * 8;
    short8 pk;
    #pragma unroll
    for (int j = 0; j < 8; ++j) {
      int k = k0 + j;
      float v = (k < 512) ? Wih[(gr + n) * 512 + k] : Whh[(gr + n) * 512 + (k - 512)];
      pk[j] = (short)f2bf(v);
    }
    wlds[blk * 64 + l] = pk;
  }

  float hreg[2][4];
  const float* hin = layer ? h2in : h1in;
  #pragma unroll
  for (int rf = 0; rf < 2; ++rf)
    #pragma unroll
    for (int q = 0; q < 4; ++q)
      hreg[rf][q] = hin[(rb * 128 + (2 * w + rf) * 16 + quad * 4 + q) * 512 + n0 + m16];

  const int nn = n0 + m16;
  const float bias_r  = bih[nn] + bhh[nn];
  const float bias_z  = bih[512 + nn] + bhh[512 + nn];
  const float bias_in = bih[1024 + nn];
  const float bias_hn = bhh[1024 + nn];
  const float wfc  = Wfc[nn];
  const float bfcv = bfc[0];

  // init barrier: ONE-TIME release (wbl2) + acquire (inv) so init data is
  // MALL-visible everywhere; steady state then needs no cache maintenance.
  __syncthreads();
  if (tid == 0) {
    __builtin_amdgcn_fence(__ATOMIC_RELEASE, "agent");
    __hip_atomic_fetch_add(cinit, 1u, __ATOMIC_RELAXED, __HIP_MEMORY_SCOPE_AGENT);
    while (__hip_atomic_load(cinit, __ATOMIC_RELAXED, __HIP_MEMORY_SCOPE_AGENT) < 256u)
      __builtin_amdgcn_s_sleep(1);
    __builtin_amdgcn_fence(__ATOMIC_ACQUIRE, "agent");
  }
  __syncthreads();

  const int arow0 = rb * 128 + (2 * w) * 16 + m16;
  const int arow1 = arow0 + 16;

  if (layer == 0) {
    // =================== producer: h1(u) ===================
    for (int u = 0; u < 64; ++u) {
      f32x4 acc[2][4] = {};
      // x-half: plain cached loads (immutable data, L1-friendly), pre-wait
      {
        const int c = u & 1;
        const u16* xc = c ? x1 : x0;
        const u32* pa0 = (const u32*)(xc + (size_t)arow0 * 576 + (u - c) + quad * 8);
        const u32* pa1 = (const u32*)(xc + (size_t)arow1 * 576 + (u - c) + quad * 8);
        #pragma unroll
        for (int s = 0; s < 16; ++s) {
          union { short8 v; u32 u4[4]; } a0, a1;
          #pragma unroll
          for (int j = 0; j < 4; ++j) { a0.u4[j] = pa0[s * 16 + j]; a1.u4[j] = pa1[s * 16 + j]; }
          short8 br = wlds[(s)      * 64 + lane];
          short8 bz = wlds[(32 + s) * 64 + lane];
          short8 bi = wlds[(64 + s) * 64 + lane];
          acc[0][0] = MFMA(a0.v, br, acc[0][0], 0, 0, 0);
          acc[1][0] = MFMA(a1.v, br, acc[1][0], 0, 0, 0);
          acc[0][1] = MFMA(a0.v, bz, acc[0][1], 0, 0, 0);
          acc[1][1] = MFMA(a1.v, bz, acc[1][1], 0, 0, 0);
          acc[0][2] = MFMA(a0.v, bi, acc[0][2], 0, 0, 0);
          acc[1][2] = MFMA(a1.v, bi, acc[1][2], 0, 0, 0);
        }
      }
      // wait: peers done h1(u-1); ring slot u&3 free (layer-1 past u-4)
      waits_nf(c0, 32u * (unsigned)u, c1, u >= 4 ? 32u * (unsigned)(u - 3) : 0u);
      // h-half: sc0 loads (L1-bypass, local-L2 dirty hit = fresh)
      #pragma unroll
      for (int rf = 0; rf < 2; ++rf) {
        short8 a[16];
        const u16* base = h1r + (size_t)((u + 3) & 3) * HS +
                          (size_t)(rf ? arow1 : arow0) * 512 + quad * 8;
        ldg16_sc0(a, base);
        #pragma unroll
        for (int s = 0; s < 16; ++s) {
          short8 br = wlds[(16 + s) * 64 + lane];
          short8 bz = wlds[(48 + s) * 64 + lane];
          short8 bh = wlds[(80 + s) * 64 + lane];
          acc[rf][0] = MFMA(a[s], br, acc[rf][0], 0, 0, 0);
          acc[rf][1] = MFMA(a[s], bz, acc[rf][1], 0, 0, 0);
          acc[rf][3] = MFMA(a[s], bh, acc[rf][3], 0, 0, 0);
        }
      }
      // gates + publish: plain store (local ring) + sc0sc1 mirror (MALL)
      {
        u16* hw = h1r + (size_t)(u & 3) * HS;
        u32* hm = (u32*)(h1m + (size_t)(u & 3) * HS);
        #pragma unroll
        for (int rf = 0; rf < 2; ++rf)
          #pragma unroll
          for (int q = 0; q < 4; ++q) {
            float rg = sigm(acc[rf][0][q] + bias_r);
            float zg = sigm(acc[rf][1][q] + bias_z);
            float ng = tanhf(acc[rf][2][q] + bias_in + rg * (acc[rf][3][q] + bias_hn));
            float hv = (1.0f - zg) * ng + zg * hreg[rf][q];
            hreg[rf][q] = hv;
            int row = rb * 128 + (2 * w + rf) * 16 + quad * 4 + q;
            u16 b = f2bf(hv);
            hw[row * 512 + nn] = b;
            int pb = __shfl_xor((int)(u32)b, 1);
            if (!(m16 & 1))
              stg_sc01(&hm[(row * 512 + nn) >> 1], (u32)b | ((u32)(u16)pb << 16));
          }
      }
      asm volatile("s_waitcnt vmcnt(0)" ::: "memory");  // mirror at MALL before inc
      __syncthreads();
      if (tid == 0)
        __hip_atomic_fetch_add(c0, 1u, __ATOMIC_RELAXED, __HIP_MEMORY_SCOPE_AGENT);
    }
  } else {
    // =================== consumer: h2(v) + y(v) ===================
    for (int v = 0; v < 64; ++v) {
      f32x4 acc[2][4] = {};
      waits_nf(c1, 32u * (unsigned)v, c0, 32u * (unsigned)(v + 1));
      // h2-half: sc0 (local L2 dirty = fresh)
      #pragma unroll
      for (int rf = 0; rf < 2; ++rf) {
        short8 a[16];
        const u16* base = h2r + (size_t)((v + 3) & 3) * HS +
                          (size_t)(rf ? arow1 : arow0) * 512 + quad * 8;
        ldg16_sc0(a, base);
        #pragma unroll
        for (int s = 0; s < 16; ++s) {
          short8 br = wlds[(16 + s) * 64 + lane];
          short8 bz = wlds[(48 + s) * 64 + lane];
          short8 bh = wlds[(80 + s) * 64 + lane];
          acc[rf][0] = MFMA(a[s], br, acc[rf][0], 0, 0, 0);
          acc[rf][1] = MFMA(a[s], bz, acc[rf][1], 0, 0, 0);
          acc[rf][3] = MFMA(a[s], bh, acc[rf][3], 0, 0, 0);
        }
      }
      // h1-half: sc0sc1 (MALL-direct, fresh by construction, no inv needed)
      #pragma unroll
      for (int rf = 0; rf < 2; ++rf) {
        short8 a[16];
        const u16* base = h1m + (size_t)(v & 3) * HS +
                          (size_t)(rf ? arow1 : arow0) * 512 + quad * 8;
        ldg16_sc01(a, base);
        #pragma unroll
        for (int s = 0; s < 16; ++s) {
          short8 br = wlds[(s)      * 64 + lane];
          short8 bz = wlds[(32 + s) * 64 + lane];
          short8 bi = wlds[(64 + s) * 64 + lane];
          acc[rf][0] = MFMA(a[s], br, acc[rf][0], 0, 0, 0);
          acc[rf][1] = MFMA(a[s], bz, acc[rf][1], 0, 0, 0);
          acc[rf][2] = MFMA(a[s], bi, acc[rf][2], 0, 0, 0);
        }
      }
      // gates + publish h2(v) (plain, local ring)
      {
        u16* hw = h2r + (size_t)(v & 3) * HS;
        #pragma unroll
        for (int rf = 0; rf < 2; ++rf)
          #pragma unroll
          for (int q = 0; q < 4; ++q) {
            float rg = sigm(acc[rf][0][q] + bias_r);
            float zg = sigm(acc[rf][1][q] + bias_z);
            float ng = tanhf(acc[rf][2][q] + bias_in + rg * (acc[rf][3][q] + bias_hn));
            float hv = (1.0f - zg) * ng + zg * hreg[rf][q];
            hreg[rf][q] = hv;
            int row = rb * 128 + (2 * w + rf) * 16 + quad * 4 + q;
            hw[row * 512 + nn] = f2bf(hv);
          }
      }
      __syncthreads();
      if (tid == 0)
        __hip_atomic_fetch_add(c1, 1u, __ATOMIC_RELAXED, __HIP_MEMORY_SCOPE_AGENT);
      // y after arrive: atomics drain overlapped with next poll
      #pragma unroll
      for (int rf = 0; rf < 2; ++rf)
        #pragma unroll
        for (int q = 0; q < 4; ++q) {
          float yv = hreg[rf][q] * wfc;
          yv += __shfl_xor(yv, 1);
          yv += __shfl_xor(yv, 2);
          yv += __shfl_xor(yv, 4);
          yv += __shfl_xor(yv, 8);
          if (m16 == 0) {
            int row = rb * 128 + (2 * w + rf) * 16 + quad * 4 + q;
            atomicAdd(&out[row * 64 + v], yv + (n0 == 0 ? bfcv : 0.0f));
          }
        }
    }
  }

  // final hidden states from registers (fp32 exact)
  float* hout = out + 32768 + layer * (512 * 512);
  #pragma unroll
  for (int rf = 0; rf < 2; ++rf)
    #pragma unroll
    for (int q = 0; q < 4; ++q) {
      int row = rb * 128 + (2 * w + rf) * 16 + quad * 4 + q;
      hout[row * 512 + nn] = hreg[rf][q];
    }
}

extern "C" void kernel_launch(void* const* d_in, const int* in_sizes, int n_in,
                              void* d_out, int out_size, void* d_ws, size_t ws_size,
                              hipStream_t stream) {
  (void)in_sizes; (void)n_in; (void)out_size; (void)ws_size;
  hipMemsetAsync(d_out, 0, 32768 * sizeof(float), stream);   // y accumulators
  hipMemsetAsync(d_ws, 0, 4096, stream);                     // arrival counters
  unsigned* bar = (unsigned*)d_ws;
  u16* wsb = (u16*)((char*)d_ws + 4096);
  gru_fused<<<256, 256, 0, stream>>>(
      (const float*)d_in[0], (const float*)d_in[1], (const float*)d_in[2],
      (const float*)d_in[3], (const float*)d_in[4], (const float*)d_in[5], (const float*)d_in[6],
      (const float*)d_in[7], (const float*)d_in[8], (const float*)d_in[9], (const float*)d_in[10],
      (const float*)d_in[11], (const float*)d_in[12],
      (float*)d_out, wsb, bar);
}